// Round 10
// baseline (305.151 us; speedup 1.0000x reference)
//
#include <hip/hip_runtime.h>

typedef _Float16 v8h __attribute__((ext_vector_type(8)));
typedef float    v4f __attribute__((ext_vector_type(4)));

#define MFMA16(a, b, c) __builtin_amdgcn_mfma_f32_16x16x32_f16((a), (b), (c), 0, 0, 0)

// Weight-fragment table in d_ws: 154 fragments, layout [frag][lane] of 8 x f16 (16B).
// Non-zero 32(k) x 16(n) tiles of the 480x480 block-diagonal Wbig:
//   ot 0..7   (cols   0..127): kt 0..3   fbase = ot*4
//   ot 8..19  (cols 128..319): kt 4..9   fbase = 32 + (ot-8)*6
//   ot 20..29 (cols 320..479): kt 10..14 fbase = 104 + (ot-20)*5
// Fragment convention (A and B slots identical): lane l, elem e holds
// k = kt*32 + (l>>4)*8 + e; other dim = l&15.
// SWAPPED use: W-frag in A slot, x-frag in B slot -> lane l, reg j =
// out[row l&15][col ot*16 + (l>>4)*4 + j] -> one float4 store per ot.

__global__ void build_frags_k(const float* __restrict__ W0, const float* __restrict__ W1,
                              const float* __restrict__ W2, v8h* __restrict__ frag) {
  const int f = blockIdx.x;
  const int lane = threadIdx.x;
  int ot, kt;
  if (f < 32)       { ot = f >> 2;           kt = f & 3; }
  else if (f < 104) { int q = f - 32;  ot = 8 + q / 6;  kt = 4 + q % 6; }
  else              { int q = f - 104; ot = 20 + q / 5; kt = 10 + q % 5; }
  const int n  = ot * 16 + (lane & 15);
  const int kb = kt * 32 + (lane >> 4) * 8;
  v8h v;
#pragma unroll
  for (int e = 0; e < 8; ++e) {
    const int k = kb + e;
    float wv = 0.0f;
    if (k < 128) {
      if (n < 128) wv = W0[k * 128 + n] * 0.08838834764831845f;           // 1/sqrt(128)
    } else if (k < 320) {
      if (n >= 128 && n < 320) {
        const int i = k - 128, o = n - 128;
        if (i % 3 == o % 3) wv = W1[(i / 3) * 64 + (o / 3)] * 0.125f;     // 1/sqrt(64)
      }
    } else {
      if (n >= 320) {
        const int i = k - 320, o = n - 320;
        if (i % 5 == o % 5) wv = W2[(i / 5) * 32 + (o / 5)] * 0.17677669529663687f; // 1/sqrt(32)
      }
    }
    v[e] = (_Float16)wv;
  }
  frag[f * 64 + lane] = v;
}

// Max-TLP, zero-LDS, zero-barrier: 256-thread blocks = 4 independent waves =
// 2 tiles x 2 ot-parities. Each wave streams x ONE k-tile at a time (x-frag
// dies within its 4-6 MFMAs -> nothing to remat, unlike round 3's a[15]),
// accumulates per-col-block acc registers, stores each ot when done.
// Parity twin re-reads the same 30KB x tile -> L1 hit (32KB L1).
// Target <=128 VGPR -> 16 waves/CU: 16 desynchronized memory streams per CU
// instead of the 8-wave barrier convoy that plateaued at ~175us (HBM 31%,
// all pipes idle).
__global__ __launch_bounds__(256, 4) void irrep_linear_k(
    const float* __restrict__ x, const v8h* __restrict__ frag, float* __restrict__ out) {
  const int t    = threadIdx.x;
  const int lane = t & 63;
  const int w    = t >> 6;
  const size_t tile = (size_t)blockIdx.x * 2 + (w >> 1);   // 16-row tile
  const int par  = w & 1;                                  // ot parity
  const int r16  = lane & 15;
  const int g    = lane >> 4;

  // lane's x granule-pair base: row tile*16+r16, float4-granule g*2 (+kt*8)
  const float4* xv = reinterpret_cast<const float4*>(x) + (tile * 16 + (size_t)r16) * 120 + g * 2;
  float* const ob  = out + (tile * 16 + (size_t)r16) * 480 + (size_t)g * 4;

#define LDX(kt, dst)                                                         \
  {                                                                          \
    const float4 lo = xv[(kt) * 8];                                          \
    const float4 hi = xv[(kt) * 8 + 1];                                      \
    v8h v_;                                                                  \
    v_[0] = (_Float16)lo.x; v_[1] = (_Float16)lo.y;                          \
    v_[2] = (_Float16)lo.z; v_[3] = (_Float16)lo.w;                          \
    v_[4] = (_Float16)hi.x; v_[5] = (_Float16)hi.y;                          \
    v_[6] = (_Float16)hi.z; v_[7] = (_Float16)hi.w;                          \
    dst = v_;                                                                \
  }

  {  // col-block 0: cols 0..127, kts 0..3, ots {par, par+2, par+4, par+6}
    v4f acc[4] = {{0.f,0.f,0.f,0.f},{0.f,0.f,0.f,0.f},{0.f,0.f,0.f,0.f},{0.f,0.f,0.f,0.f}};
#pragma unroll
    for (int kt = 0; kt < 4; ++kt) {
      v8h xa; LDX(kt, xa);
#pragma unroll
      for (int i = 0; i < 4; ++i) {
        const int ot = par + 2 * i;
        acc[i] = MFMA16(frag[(ot * 4 + kt) * 64 + lane], xa, acc[i]);
      }
    }
#pragma unroll
    for (int i = 0; i < 4; ++i)
      *reinterpret_cast<v4f*>(ob + (par + 2 * i) * 16) = acc[i];
  }
  {  // col-block 1: cols 128..319, kts 4..9, ots {8+par+2i, i=0..5}
    v4f acc[6] = {{0.f,0.f,0.f,0.f},{0.f,0.f,0.f,0.f},{0.f,0.f,0.f,0.f},
                  {0.f,0.f,0.f,0.f},{0.f,0.f,0.f,0.f},{0.f,0.f,0.f,0.f}};
#pragma unroll
    for (int kt = 4; kt < 10; ++kt) {
      v8h xa; LDX(kt, xa);
#pragma unroll
      for (int i = 0; i < 6; ++i) {
        const int ot = 8 + par + 2 * i;
        acc[i] = MFMA16(frag[(32 + (ot - 8) * 6 + (kt - 4)) * 64 + lane], xa, acc[i]);
      }
    }
#pragma unroll
    for (int i = 0; i < 6; ++i)
      *reinterpret_cast<v4f*>(ob + (8 + par + 2 * i) * 16) = acc[i];
  }
  {  // col-block 2: cols 320..479, kts 10..14, ots {20+par+2i, i=0..4}
    v4f acc[5] = {{0.f,0.f,0.f,0.f},{0.f,0.f,0.f,0.f},{0.f,0.f,0.f,0.f},
                  {0.f,0.f,0.f,0.f},{0.f,0.f,0.f,0.f}};
#pragma unroll
    for (int kt = 10; kt < 15; ++kt) {
      v8h xa; LDX(kt, xa);
#pragma unroll
      for (int i = 0; i < 5; ++i) {
        const int ot = 20 + par + 2 * i;
        acc[i] = MFMA16(frag[(104 + (ot - 20) * 5 + (kt - 10)) * 64 + lane], xa, acc[i]);
      }
    }
#pragma unroll
    for (int i = 0; i < 5; ++i)
      *reinterpret_cast<v4f*>(ob + (20 + par + 2 * i) * 16) = acc[i];
  }
#undef LDX
}

extern "C" void kernel_launch(void* const* d_in, const int* in_sizes, int n_in,
                              void* d_out, int out_size, void* d_ws, size_t ws_size,
                              hipStream_t stream) {
  const float* x  = (const float*)d_in[0];
  const float* W0 = (const float*)d_in[1];
  const float* W1 = (const float*)d_in[2];
  const float* W2 = (const float*)d_in[3];
  float* out = (float*)d_out;
  v8h* frag = (v8h*)d_ws;   // 154 * 64 * 16 B = 157,696 B

  build_frags_k<<<154, 64, 0, stream>>>(W0, W1, W2, frag);

  const int N = in_sizes[0] / 480;      // 200000
  const int nblk = N / 32;              // 6250 blocks: 2 tiles x 2 parities each
  irrep_linear_k<<<nblk, 256, 0, stream>>>(x, frag, out);
}

// Round 11
// 206.848 us; speedup vs baseline: 1.4752x; 1.4752x over previous
//
#include <hip/hip_runtime.h>

typedef _Float16 v8h __attribute__((ext_vector_type(8)));
typedef float    v4f __attribute__((ext_vector_type(4)));

#define MFMA16(a, b, c) __builtin_amdgcn_mfma_f32_16x16x32_f16((a), (b), (c), 0, 0, 0)

#define GLL16(gptr, lptr)                                                        \
  __builtin_amdgcn_global_load_lds((const __attribute__((address_space(1))) void*)(gptr), \
                                   (__attribute__((address_space(3))) void*)(lptr), 16, 0, 0)

// Weight-fragment table in d_ws: 154 fragments, layout [frag][lane] of 8 x f16 (16B).
// Non-zero 32(k) x 16(n) tiles of the 480x480 block-diagonal Wbig:
//   ot 0..7   (cols   0..127): kt 0..3   fbase = ot*4
//   ot 8..19  (cols 128..319): kt 4..9   fbase = 32 + (ot-8)*6
//   ot 20..29 (cols 320..479): kt 10..14 fbase = 104 + (ot-20)*5
// Fragment convention (A and B slots identical): lane l, elem e holds
// k = kt*32 + (l>>4)*8 + e; other dim = l&15.
// SWAPPED use: W-frag in A slot, x-frag in B slot -> lane l, reg j =
// out[row l&15][col ot*16 + (l>>4)*4 + j] -> one float4 store per ot.

__global__ void build_frags_k(const float* __restrict__ W0, const float* __restrict__ W1,
                              const float* __restrict__ W2, v8h* __restrict__ frag) {
  const int f = blockIdx.x;
  const int lane = threadIdx.x;
  int ot, kt;
  if (f < 32)       { ot = f >> 2;           kt = f & 3; }
  else if (f < 104) { int q = f - 32;  ot = 8 + q / 6;  kt = 4 + q % 6; }
  else              { int q = f - 104; ot = 20 + q / 5; kt = 10 + q % 5; }
  const int n  = ot * 16 + (lane & 15);
  const int kb = kt * 32 + (lane >> 4) * 8;
  v8h v;
#pragma unroll
  for (int e = 0; e < 8; ++e) {
    const int k = kb + e;
    float wv = 0.0f;
    if (k < 128) {
      if (n < 128) wv = W0[k * 128 + n] * 0.08838834764831845f;           // 1/sqrt(128)
    } else if (k < 320) {
      if (n >= 128 && n < 320) {
        const int i = k - 128, o = n - 128;
        if (i % 3 == o % 3) wv = W1[(i / 3) * 64 + (o / 3)] * 0.125f;     // 1/sqrt(64)
      }
    } else {
      if (n >= 320) {
        const int i = k - 320, o = n - 320;
        if (i % 5 == o % 5) wv = W2[(i / 5) * 32 + (o / 5)] * 0.17677669529663687f; // 1/sqrt(32)
      }
    }
    v[e] = (_Float16)wv;
  }
  frag[f * 64 + lane] = v;
}

// Persistent 512-thread blocks (8 waves), 1/CU. 16-row tiles, FOUR LDS buffers
// (4 x 30720B = 120KB): reads stay ~3 tiles (90KB/CU) outstanding at all times
// -> the HBM read stream never goes burst-idle (the round-9 limiter: depth-1
// prefetch left the read pipe idle ~60% of each 7us period).
// Wave w owns ots {w, 8+w, 16+w[, 24+w]} with register-resident B-frags.
// vmcnt: steady wait 3G+3S retires exactly gll(t) (3 tiles of reads + 3 tiles
// of stores remain in flight). Prologue waits grow 3G / 3G+S / 3G+2S; epilogue
// waits S (smaller N = safe over-wait).
template <int V>
__device__ __forceinline__ void wave_main(const float* __restrict__ x,
                                          const v8h* __restrict__ frag,
                                          float* __restrict__ out,
                                          unsigned char* sm, int t, int t0, int t1) {
  const int lane = t & 63;
  const int w    = t >> 6;
  const int r16  = lane & 15;
  const int g    = lane >> 4;

  constexpr int G = (V == 2) ? 3 : 4;            // gll per wave per tile
  constexpr int S = (V == 2) ? 3 : 4;            // stores per wave per tile

  // ---- persistent B-fragments (compile-time register indices) ----
  constexpr int NF = (V == 0) ? 21 : (V == 1) ? 20 : 15;
  v8h f[NF];
  {
    const int fb0 = w * 4;
    const int fb1 = 32 + w * 6;
#pragma unroll
    for (int k = 0; k < 4; ++k) f[k] = frag[(fb0 + k) * 64 + lane];
#pragma unroll
    for (int k = 0; k < 6; ++k) f[4 + k] = frag[(fb1 + k) * 64 + lane];
    if constexpr (V == 0) {
      const int fb2 = 32 + (8 + w) * 6;       // ot 16+w (cb1)
      const int fb3 = 104 + (4 + w) * 5;      // ot 24+w (cb2)
#pragma unroll
      for (int k = 0; k < 6; ++k) f[10 + k] = frag[(fb2 + k) * 64 + lane];
#pragma unroll
      for (int k = 0; k < 5; ++k) f[16 + k] = frag[(fb3 + k) * 64 + lane];
    } else if constexpr (V == 1) {
      const int fb2 = 104 + (w - 4) * 5;      // ot 16+w (cb2)
      const int fb3 = 104 + (w + 4) * 5;      // ot 24+w (cb2)
#pragma unroll
      for (int k = 0; k < 5; ++k) f[10 + k] = frag[(fb2 + k) * 64 + lane];
#pragma unroll
      for (int k = 0; k < 5; ++k) f[15 + k] = frag[(fb3 + k) * 64 + lane];
    } else {
      const int fb2 = 104 + (w - 4) * 5;      // ot 16+w (cb2)
#pragma unroll
      for (int k = 0; k < 5; ++k) f[10 + k] = frag[(fb2 + k) * 64 + lane];
    }
  }

  // ---- staging: 16 rows x 1920B = 1920 granules; G gll per wave ----
  auto stage = [&](int tt) {
    const unsigned char* xt = (const unsigned char*)x + (size_t)tt * 30720u;
    unsigned char* buf = sm + (size_t)(tt & 3) * 30720u;
#pragma unroll
    for (int i = 0; i < 4; ++i) {
      if (i < 3 || w < 6) {                    // wave-uniform (i=3: waves 0..5)
        const unsigned gl = (unsigned)(i * 512 + t);
        const unsigned r  = gl / 120u;
        const unsigned j  = gl - r * 120u;
        GLL16(xt + r * 1920u + ((j ^ (r & 7u)) << 4), buf + i * 8192 + w * 1024);
      }
    }
  };

#define LDAF(kt, dst)                                                                       \
  {                                                                                         \
    const unsigned j0 = (unsigned)((kt) * 8 + g * 2);                                       \
    const float4 lo = *reinterpret_cast<const float4*>(smc + rb + (((j0) ^ q) << 4));       \
    const float4 hi = *reinterpret_cast<const float4*>(smc + rb + ((((j0) + 1) ^ q) << 4)); \
    v8h v_;                                                                                 \
    v_[0] = (_Float16)lo.x; v_[1] = (_Float16)lo.y;                                         \
    v_[2] = (_Float16)lo.z; v_[3] = (_Float16)lo.w;                                         \
    v_[4] = (_Float16)hi.x; v_[5] = (_Float16)hi.y;                                         \
    v_[6] = (_Float16)hi.z; v_[7] = (_Float16)hi.w;                                         \
    dst = v_;                                                                               \
  }

  auto compute = [&](int tt) {
    const unsigned char* smc = sm + (size_t)(tt & 3) * 30720u;
    const unsigned rb = (unsigned)r16 * 1920u;
    const unsigned q  = (unsigned)(r16 & 7u);
    float* const ob = out + ((size_t)tt * 16 + r16) * 480 + g * 4;
    {  // cb0: kts 0..3, ot = w
      v8h x0[4];
#pragma unroll
      for (int k = 0; k < 4; ++k) LDAF(k, x0[k]);
      v4f a0 = {0.f, 0.f, 0.f, 0.f};
#pragma unroll
      for (int k = 0; k < 4; ++k) a0 = MFMA16(f[k], x0[k], a0);
      *reinterpret_cast<v4f*>(ob + w * 16) = a0;
    }
    {  // cb1: kts 4..9, ot 8+w (and 16+w for V=0)
      v8h x1[6];
#pragma unroll
      for (int k = 0; k < 6; ++k) LDAF(4 + k, x1[k]);
      v4f a1 = {0.f, 0.f, 0.f, 0.f};
#pragma unroll
      for (int k = 0; k < 6; ++k) a1 = MFMA16(f[4 + k], x1[k], a1);
      *reinterpret_cast<v4f*>(ob + (8 + w) * 16) = a1;
      if constexpr (V == 0) {
        v4f a2 = {0.f, 0.f, 0.f, 0.f};
#pragma unroll
        for (int k = 0; k < 6; ++k) a2 = MFMA16(f[10 + k], x1[k], a2);
        *reinterpret_cast<v4f*>(ob + (16 + w) * 16) = a2;
      }
    }
    {  // cb2: kts 10..14
      v8h x2[5];
#pragma unroll
      for (int k = 0; k < 5; ++k) LDAF(10 + k, x2[k]);
      if constexpr (V == 0) {
        v4f a3 = {0.f, 0.f, 0.f, 0.f};
#pragma unroll
        for (int k = 0; k < 5; ++k) a3 = MFMA16(f[16 + k], x2[k], a3);
        *reinterpret_cast<v4f*>(ob + (24 + w) * 16) = a3;
      } else if constexpr (V == 1) {
        v4f a2 = {0.f, 0.f, 0.f, 0.f}, a3 = {0.f, 0.f, 0.f, 0.f};
#pragma unroll
        for (int k = 0; k < 5; ++k) {
          a2 = MFMA16(f[10 + k], x2[k], a2);
          a3 = MFMA16(f[15 + k], x2[k], a3);
        }
        *reinterpret_cast<v4f*>(ob + (16 + w) * 16) = a2;
        *reinterpret_cast<v4f*>(ob + (24 + w) * 16) = a3;
      } else {
        v4f a2 = {0.f, 0.f, 0.f, 0.f};
#pragma unroll
        for (int k = 0; k < 5; ++k) a2 = MFMA16(f[10 + k], x2[k], a2);
        *reinterpret_cast<v4f*>(ob + (16 + w) * 16) = a2;
      }
    }
  };

#define PIPE_ITER(TT, N)                                        \
  {                                                             \
    asm volatile("s_waitcnt vmcnt(%0)" :: "n"(N) : "memory");   \
    __builtin_amdgcn_s_barrier();                               \
    compute(TT);                                                \
    __builtin_amdgcn_s_barrier();                               \
  }

  // ---- 4-deep pipelined tile loop (t1-t0 >= 7 guaranteed: 48/49 tiles) ----
  stage(t0); stage(t0 + 1); stage(t0 + 2);
  stage(t0 + 3); PIPE_ITER(t0,     3 * G)
  stage(t0 + 4); PIPE_ITER(t0 + 1, 3 * G + S)
  stage(t0 + 5); PIPE_ITER(t0 + 2, 3 * G + 2 * S)
  for (int tt = t0 + 3; tt < t1 - 3; ++tt) {
    stage(tt + 3);
    PIPE_ITER(tt, 3 * G + 3 * S)
  }
  for (int tt = t1 - 3; tt < t1; ++tt) {
    PIPE_ITER(tt, S)
  }
#undef PIPE_ITER
#undef LDAF
}

__global__ __launch_bounds__(512, 2) void irrep_linear_k(
    const float* __restrict__ x, const v8h* __restrict__ frag, float* __restrict__ out,
    int base_tpb, int rem) {
  __shared__ __align__(16) unsigned char sm[4 * 30720];
  const int t = threadIdx.x;
  const int b = blockIdx.x;
  const int t0 = b * base_tpb + (b < rem ? b : rem);
  const int t1 = t0 + base_tpb + (b < rem ? 1 : 0);
  const int w = t >> 6;
  if (w < 4)      wave_main<0>(x, frag, out, sm, t, t0, t1);
  else if (w < 6) wave_main<1>(x, frag, out, sm, t, t0, t1);
  else            wave_main<2>(x, frag, out, sm, t, t0, t1);
}

extern "C" void kernel_launch(void* const* d_in, const int* in_sizes, int n_in,
                              void* d_out, int out_size, void* d_ws, size_t ws_size,
                              hipStream_t stream) {
  const float* x  = (const float*)d_in[0];
  const float* W0 = (const float*)d_in[1];
  const float* W1 = (const float*)d_in[2];
  const float* W2 = (const float*)d_in[3];
  float* out = (float*)d_out;
  v8h* frag = (v8h*)d_ws;   // 154 * 64 * 16 B = 157,696 B

  build_frags_k<<<154, 64, 0, stream>>>(W0, W1, W2, frag);

  const int N = in_sizes[0] / 480;        // 200000
  const int n_tiles = N / 16;             // 12500 tiles of 16 rows
  const int nblk = 256;                   // persistent, 1 block/CU
  const int base_tpb = n_tiles / nblk;    // 48
  const int rem = n_tiles - base_tpb * nblk;  // 212
  irrep_linear_k<<<nblk, 512, 0, stream>>>(x, frag, out, base_tpb, rem);
}

// Round 13
// 172.762 us; speedup vs baseline: 1.7663x; 1.1973x over previous
//
#include <hip/hip_runtime.h>

typedef _Float16 v8h __attribute__((ext_vector_type(8)));
typedef float    v4f __attribute__((ext_vector_type(4)));

#define MFMA16(a, b, c) __builtin_amdgcn_mfma_f32_16x16x32_f16((a), (b), (c), 0, 0, 0)

#define GLL16(gptr, lptr)                                                        \
  __builtin_amdgcn_global_load_lds((const __attribute__((address_space(1))) void*)(gptr), \
                                   (__attribute__((address_space(3))) void*)(lptr), 16, 0, 0)

// Weight-fragment table in d_ws: 154 fragments, layout [frag][lane] of 8 x f16 (16B).
// Non-zero 32(k) x 16(n) tiles of the 480x480 block-diagonal Wbig:
//   ot 0..7   (cols   0..127): kt 0..3   fbase = ot*4
//   ot 8..19  (cols 128..319): kt 4..9   fbase = 32 + (ot-8)*6
//   ot 20..29 (cols 320..479): kt 10..14 fbase = 104 + (ot-20)*5
// Fragment convention (A and B slots identical): lane l, elem e holds
// k = kt*32 + (l>>4)*8 + e; other dim = l&15.
// SWAPPED use: W-frag in A slot, x-frag in B slot -> lane l, reg j =
// out[row l&15][col ot*16 + (l>>4)*4 + j] -> one float4 store per ot per slab.

__global__ void build_frags_k(const float* __restrict__ W0, const float* __restrict__ W1,
                              const float* __restrict__ W2, v8h* __restrict__ frag) {
  const int f = blockIdx.x;
  const int lane = threadIdx.x;
  int ot, kt;
  if (f < 32)       { ot = f >> 2;           kt = f & 3; }
  else if (f < 104) { int q = f - 32;  ot = 8 + q / 6;  kt = 4 + q % 6; }
  else              { int q = f - 104; ot = 20 + q / 5; kt = 10 + q % 5; }
  const int n  = ot * 16 + (lane & 15);
  const int kb = kt * 32 + (lane >> 4) * 8;
  v8h v;
#pragma unroll
  for (int e = 0; e < 8; ++e) {
    const int k = kb + e;
    float wv = 0.0f;
    if (k < 128) {
      if (n < 128) wv = W0[k * 128 + n] * 0.08838834764831845f;           // 1/sqrt(128)
    } else if (k < 320) {
      if (n >= 128 && n < 320) {
        const int i = k - 128, o = n - 128;
        if (i % 3 == o % 3) wv = W1[(i / 3) * 64 + (o / 3)] * 0.125f;     // 1/sqrt(64)
      }
    } else {
      if (n >= 320) {
        const int i = k - 320, o = n - 320;
        if (i % 5 == o % 5) wv = W2[(i / 5) * 32 + (o / 5)] * 0.17677669529663687f; // 1/sqrt(32)
      }
    }
    v[e] = (_Float16)wv;
  }
  frag[f * 64 + lane] = v;
}

// Persistent 512-thread blocks, 1/CU, 32-row tiles double-buffered in LDS
// (2 x 61440B) via global_load_lds + source-side bank swizzle (round-9
// verified skeleton: counted vmcnt G / G+S / S, two barriers per tile).
//
// NEW: waves are partitioned by COL-BLOCK, so each wave reads only its own
// k-range from LDS (b128 reads per tile: 480 -> 168, conversions likewise):
//   V=0 (w 0,1):  cb0, ots {w+2i, i<4},       kts 0..3,   16 frags, S=8
//   V=1 (w 2..5): cb1, ots {6+w+4i, i<3},     kts 4..9,   18 frags, S=6
//   V=2 (w 6,7):  cb2, ots {14+w+2i, i<5},    kts 10..14, 25 frags, S=10
// G (gll per wave per tile) = 8 for w<4, 7 for w>=4 (staging split).
template <int V, int G>
__device__ __forceinline__ void wave_main(const float* __restrict__ x,
                                          const v8h* __restrict__ frag,
                                          float* __restrict__ out,
                                          unsigned char* sm, int t, int t0, int t1) {
  const int lane = t & 63;
  const int w    = t >> 6;
  const int r16  = lane & 15;
  const int g    = lane >> 4;

  constexpr int S  = (V == 0) ? 8 : (V == 1) ? 6 : 10;   // stores per tile
  constexpr int NF = (V == 0) ? 16 : (V == 1) ? 18 : 25; // resident frags

  // ---- persistent B-fragments (compile-time indices) ----
  v8h f[NF];
  if constexpr (V == 0) {
#pragma unroll
    for (int i = 0; i < 4; ++i)
#pragma unroll
      for (int k = 0; k < 4; ++k)
        f[i * 4 + k] = frag[((w + 2 * i) * 4 + k) * 64 + lane];
  } else if constexpr (V == 1) {
#pragma unroll
    for (int i = 0; i < 3; ++i)
#pragma unroll
      for (int k = 0; k < 6; ++k)
        f[i * 6 + k] = frag[(32 + (w - 2 + 4 * i) * 6 + k) * 64 + lane];
  } else {
#pragma unroll
    for (int i = 0; i < 5; ++i)
#pragma unroll
      for (int k = 0; k < 5; ++k)
        f[i * 5 + k] = frag[(104 + (w - 6 + 2 * i) * 5 + k) * 64 + lane];
  }

  // ---- staging: 32 rows x 1920B = 3840 granules; G gll per wave ----
  auto stage = [&](int tt, int bsel) {
    const unsigned char* xt = (const unsigned char*)x + (size_t)tt * 61440u;
    unsigned char* buf = sm + bsel * 61440;
#pragma unroll
    for (int i = 0; i < 8; ++i) {
      if (i < 7 || t < 256) {                  // wave-uniform; waves 0..3 do i=7
        const unsigned gl = (unsigned)(i * 512 + t);
        const unsigned r  = gl / 120u;
        const unsigned j  = gl - r * 120u;
        GLL16(xt + r * 1920u + ((j ^ (r & 7u)) << 4), buf + i * 8192 + w * 1024);
      }
    }
  };

#define LDAF(kt, dst)                                                                       \
  {                                                                                         \
    const unsigned j0 = (unsigned)((kt) * 8 + g * 2);                                       \
    const float4 lo = *reinterpret_cast<const float4*>(smc + rb + (((j0) ^ q) << 4));       \
    const float4 hi = *reinterpret_cast<const float4*>(smc + rb + ((((j0) + 1) ^ q) << 4)); \
    v8h v_;                                                                                 \
    v_[0] = (_Float16)lo.x; v_[1] = (_Float16)lo.y;                                         \
    v_[2] = (_Float16)lo.z; v_[3] = (_Float16)lo.w;                                         \
    v_[4] = (_Float16)hi.x; v_[5] = (_Float16)hi.y;                                         \
    v_[6] = (_Float16)hi.z; v_[7] = (_Float16)hi.w;                                         \
    dst = v_;                                                                               \
  }

  auto compute = [&](int tt, int bsel) {
    const unsigned char* smc = sm + bsel * 61440;
#pragma unroll
    for (int sl = 0; sl < 2; ++sl) {
      const unsigned row = (unsigned)(sl * 16 + r16);
      const unsigned rb  = row * 1920u;
      const unsigned q   = row & 7u;
      float* const ob = out + ((size_t)tt * 32 + sl * 16 + r16) * 480 + g * 4;
      if constexpr (V == 0) {
        v8h xr[4];
#pragma unroll
        for (int k = 0; k < 4; ++k) LDAF(k, xr[k]);
#pragma unroll
        for (int i = 0; i < 4; ++i) {
          v4f a = {0.f, 0.f, 0.f, 0.f};
#pragma unroll
          for (int k = 0; k < 4; ++k) a = MFMA16(f[i * 4 + k], xr[k], a);
          *reinterpret_cast<v4f*>(ob + (w + 2 * i) * 16) = a;
        }
      } else if constexpr (V == 1) {
        v8h xr[6];
#pragma unroll
        for (int k = 0; k < 6; ++k) LDAF(4 + k, xr[k]);
#pragma unroll
        for (int i = 0; i < 3; ++i) {
          v4f a = {0.f, 0.f, 0.f, 0.f};
#pragma unroll
          for (int k = 0; k < 6; ++k) a = MFMA16(f[i * 6 + k], xr[k], a);
          *reinterpret_cast<v4f*>(ob + (6 + w + 4 * i) * 16) = a;
        }
      } else {
        v8h xr[5];
#pragma unroll
        for (int k = 0; k < 5; ++k) LDAF(10 + k, xr[k]);
#pragma unroll
        for (int i = 0; i < 5; ++i) {
          v4f a = {0.f, 0.f, 0.f, 0.f};
#pragma unroll
          for (int k = 0; k < 5; ++k) a = MFMA16(f[i * 5 + k], xr[k], a);
          *reinterpret_cast<v4f*>(ob + (14 + w + 2 * i) * 16) = a;
        }
      }
    }
  };

  // ---- pipelined tile loop (round-9 verified waits) ----
  stage(t0, 0);
  stage(t0 + 1, 1);
  asm volatile("s_waitcnt vmcnt(%0)" :: "n"(G) : "memory");   // retire gll(t0)
  __builtin_amdgcn_s_barrier();
  compute(t0, 0);
  __builtin_amdgcn_s_barrier();

  int tt = t0 + 1;
  for (; tt < t1 - 1; ++tt) {
    const int cur = (tt - t0) & 1;
    stage(tt + 1, cur ^ 1);
    // outstanding: gll(t)[G] + stores(t-1)[S] + gll(t+1)[G]; retire gll(t) only
    asm volatile("s_waitcnt vmcnt(%0)" :: "n"(G + S) : "memory");
    __builtin_amdgcn_s_barrier();
    compute(tt, cur);
    __builtin_amdgcn_s_barrier();
  }
  {  // final tile: retire gll(last), leave stores(prev) in flight
    const int cur = (tt - t0) & 1;
    asm volatile("s_waitcnt vmcnt(%0)" :: "n"(S) : "memory");
    __builtin_amdgcn_s_barrier();
    compute(tt, cur);
  }
#undef LDAF
}

__global__ __launch_bounds__(512, 1) void irrep_linear_k(
    const float* __restrict__ x, const v8h* __restrict__ frag, float* __restrict__ out,
    int base_tpb, int rem) {
  __shared__ __align__(16) unsigned char sm[2 * 61440];
  const int t = threadIdx.x;
  const int b = blockIdx.x;
  const int t0 = b * base_tpb + (b < rem ? b : rem);
  const int t1 = t0 + base_tpb + (b < rem ? 1 : 0);
  const int w = t >> 6;
  if (w < 2)      wave_main<0, 8>(x, frag, out, sm, t, t0, t1);
  else if (w < 4) wave_main<1, 8>(x, frag, out, sm, t, t0, t1);
  else if (w < 6) wave_main<1, 7>(x, frag, out, sm, t, t0, t1);
  else            wave_main<2, 7>(x, frag, out, sm, t, t0, t1);
}

extern "C" void kernel_launch(void* const* d_in, const int* in_sizes, int n_in,
                              void* d_out, int out_size, void* d_ws, size_t ws_size,
                              hipStream_t stream) {
  const float* x  = (const float*)d_in[0];
  const float* W0 = (const float*)d_in[1];
  const float* W1 = (const float*)d_in[2];
  const float* W2 = (const float*)d_in[3];
  float* out = (float*)d_out;
  v8h* frag = (v8h*)d_ws;   // 154 * 64 * 16 B = 157,696 B

  build_frags_k<<<154, 64, 0, stream>>>(W0, W1, W2, frag);

  const int N = in_sizes[0] / 480;        // 200000
  const int n_tiles = N / 32;             // 6250 tiles of 32 rows
  const int nblk = 256;                   // persistent, 1 block/CU
  const int base_tpb = n_tiles / nblk;    // 24
  const int rem = n_tiles - base_tpb * nblk;  // 106
  irrep_linear_k<<<nblk, 512, 0, stream>>>(x, frag, out, base_tpb, rem);
}

// Round 14
// 155.749 us; speedup vs baseline: 1.9592x; 1.1092x over previous
//
#include <hip/hip_runtime.h>

typedef _Float16 v8h __attribute__((ext_vector_type(8)));
typedef float    v4f __attribute__((ext_vector_type(4)));

#define MFMA16(a, b, c) __builtin_amdgcn_mfma_f32_16x16x32_f16((a), (b), (c), 0, 0, 0)

#define GLL16(gptr, lptr)                                                        \
  __builtin_amdgcn_global_load_lds((const __attribute__((address_space(1))) void*)(gptr), \
                                   (__attribute__((address_space(3))) void*)(lptr), 16, 0, 0)

// Weight-fragment table in d_ws: 154 fragments, layout [frag][lane] of 8 x f16 (16B).
// Non-zero 32(k) x 16(n) tiles of the 480x480 block-diagonal Wbig:
//   ot 0..7   (cols   0..127): kt 0..3   fbase = ot*4
//   ot 8..19  (cols 128..319): kt 4..9   fbase = 32 + (ot-8)*6
//   ot 20..29 (cols 320..479): kt 10..14 fbase = 104 + (ot-20)*5
// Fragment convention (A and B slots identical): lane l, elem e holds
// k = kt*32 + (l>>4)*8 + e; other dim = l&15.
// SWAPPED use: W-frag in A slot, x-frag in B slot -> lane l, reg j =
// out[row l&15][col ot*16 + (l>>4)*4 + j] -> one float4 store per ot per slab.

__global__ void build_frags_k(const float* __restrict__ W0, const float* __restrict__ W1,
                              const float* __restrict__ W2, v8h* __restrict__ frag) {
  const int f = blockIdx.x;
  const int lane = threadIdx.x;
  int ot, kt;
  if (f < 32)       { ot = f >> 2;           kt = f & 3; }
  else if (f < 104) { int q = f - 32;  ot = 8 + q / 6;  kt = 4 + q % 6; }
  else              { int q = f - 104; ot = 20 + q / 5; kt = 10 + q % 5; }
  const int n  = ot * 16 + (lane & 15);
  const int kb = kt * 32 + (lane >> 4) * 8;
  v8h v;
#pragma unroll
  for (int e = 0; e < 8; ++e) {
    const int k = kb + e;
    float wv = 0.0f;
    if (k < 128) {
      if (n < 128) wv = W0[k * 128 + n] * 0.08838834764831845f;           // 1/sqrt(128)
    } else if (k < 320) {
      if (n >= 128 && n < 320) {
        const int i = k - 128, o = n - 128;
        if (i % 3 == o % 3) wv = W1[(i / 3) * 64 + (o / 3)] * 0.125f;     // 1/sqrt(64)
      }
    } else {
      if (n >= 320) {
        const int i = k - 320, o = n - 320;
        if (i % 5 == o % 5) wv = W2[(i / 5) * 32 + (o / 5)] * 0.17677669529663687f; // 1/sqrt(32)
      }
    }
    v[e] = (_Float16)wv;
  }
  frag[f * 64 + lane] = v;
}

// Persistent 512-thread blocks, 1/CU; round-13 verified skeleton (double-
// buffered gll staging, source-side swizzle, col-block wave partition,
// counted vmcnt G / G+S / S, two barriers per tile).
//
// ONE change vs round 13: GRID-STRIDE tile assignment. Block b handles tiles
// {b, b+256, b+512, ...} so all 256 blocks walk a single contiguous ~15.7MB
// window through x and out (the copy-bench pattern), instead of 256 scattered
// private chunks (DRAM row-buffer thrash — the suspected 70%-efficiency cap).
template <int V, int G>
__device__ __forceinline__ void wave_main(const float* __restrict__ x,
                                          const v8h* __restrict__ frag,
                                          float* __restrict__ out,
                                          unsigned char* sm, int t, int b, int nc) {
  const int lane = t & 63;
  const int w    = t >> 6;
  const int r16  = lane & 15;
  const int g    = lane >> 4;

  constexpr int S  = (V == 0) ? 8 : (V == 1) ? 6 : 10;   // stores per tile
  constexpr int NF = (V == 0) ? 16 : (V == 1) ? 18 : 25; // resident frags

  // ---- persistent B-fragments (compile-time indices) ----
  v8h f[NF];
  if constexpr (V == 0) {
#pragma unroll
    for (int i = 0; i < 4; ++i)
#pragma unroll
      for (int k = 0; k < 4; ++k)
        f[i * 4 + k] = frag[((w + 2 * i) * 4 + k) * 64 + lane];
  } else if constexpr (V == 1) {
#pragma unroll
    for (int i = 0; i < 3; ++i)
#pragma unroll
      for (int k = 0; k < 6; ++k)
        f[i * 6 + k] = frag[(32 + (w - 2 + 4 * i) * 6 + k) * 64 + lane];
  } else {
#pragma unroll
    for (int i = 0; i < 5; ++i)
#pragma unroll
      for (int k = 0; k < 5; ++k)
        f[i * 5 + k] = frag[(104 + (w - 6 + 2 * i) * 5 + k) * 64 + lane];
  }

  // ---- staging: 32 rows x 1920B = 3840 granules; G gll per wave ----
  auto stage = [&](int tt, int bsel) {
    const unsigned char* xt = (const unsigned char*)x + (size_t)tt * 61440u;
    unsigned char* buf = sm + bsel * 61440;
#pragma unroll
    for (int i = 0; i < 8; ++i) {
      if (i < 7 || t < 256) {                  // wave-uniform; waves 0..3 do i=7
        const unsigned gl = (unsigned)(i * 512 + t);
        const unsigned r  = gl / 120u;
        const unsigned j  = gl - r * 120u;
        GLL16(xt + r * 1920u + ((j ^ (r & 7u)) << 4), buf + i * 8192 + w * 1024);
      }
    }
  };

#define LDAF(kt, dst)                                                                       \
  {                                                                                         \
    const unsigned j0 = (unsigned)((kt) * 8 + g * 2);                                       \
    const float4 lo = *reinterpret_cast<const float4*>(smc + rb + (((j0) ^ q) << 4));       \
    const float4 hi = *reinterpret_cast<const float4*>(smc + rb + ((((j0) + 1) ^ q) << 4)); \
    v8h v_;                                                                                 \
    v_[0] = (_Float16)lo.x; v_[1] = (_Float16)lo.y;                                         \
    v_[2] = (_Float16)lo.z; v_[3] = (_Float16)lo.w;                                         \
    v_[4] = (_Float16)hi.x; v_[5] = (_Float16)hi.y;                                         \
    v_[6] = (_Float16)hi.z; v_[7] = (_Float16)hi.w;                                         \
    dst = v_;                                                                               \
  }

  auto compute = [&](int tt, int bsel) {
    const unsigned char* smc = sm + bsel * 61440;
#pragma unroll
    for (int sl = 0; sl < 2; ++sl) {
      const unsigned row = (unsigned)(sl * 16 + r16);
      const unsigned rb  = row * 1920u;
      const unsigned q   = row & 7u;
      float* const ob = out + ((size_t)tt * 32 + sl * 16 + r16) * 480 + g * 4;
      if constexpr (V == 0) {
        v8h xr[4];
#pragma unroll
        for (int k = 0; k < 4; ++k) LDAF(k, xr[k]);
#pragma unroll
        for (int i = 0; i < 4; ++i) {
          v4f a = {0.f, 0.f, 0.f, 0.f};
#pragma unroll
          for (int k = 0; k < 4; ++k) a = MFMA16(f[i * 4 + k], xr[k], a);
          *reinterpret_cast<v4f*>(ob + (w + 2 * i) * 16) = a;
        }
      } else if constexpr (V == 1) {
        v8h xr[6];
#pragma unroll
        for (int k = 0; k < 6; ++k) LDAF(4 + k, xr[k]);
#pragma unroll
        for (int i = 0; i < 3; ++i) {
          v4f a = {0.f, 0.f, 0.f, 0.f};
#pragma unroll
          for (int k = 0; k < 6; ++k) a = MFMA16(f[i * 6 + k], xr[k], a);
          *reinterpret_cast<v4f*>(ob + (6 + w + 4 * i) * 16) = a;
        }
      } else {
        v8h xr[5];
#pragma unroll
        for (int k = 0; k < 5; ++k) LDAF(10 + k, xr[k]);
#pragma unroll
        for (int i = 0; i < 5; ++i) {
          v4f a = {0.f, 0.f, 0.f, 0.f};
#pragma unroll
          for (int k = 0; k < 5; ++k) a = MFMA16(f[i * 5 + k], xr[k], a);
          *reinterpret_cast<v4f*>(ob + (14 + w + 2 * i) * 16) = a;
        }
      }
    }
  };

  // ---- pipelined tile loop over grid-stride chunks: tile(c) = b + c*256 ----
  stage(b, 0);
  stage(b + 256, 1);
  asm volatile("s_waitcnt vmcnt(%0)" :: "n"(G) : "memory");   // retire gll(c0)
  __builtin_amdgcn_s_barrier();
  compute(b, 0);
  __builtin_amdgcn_s_barrier();

  int c = 1;
  for (; c < nc - 1; ++c) {
    stage(b + (c + 1) * 256, (c + 1) & 1);
    // outstanding: gll(c)[G] + stores(c-1)[S] + gll(c+1)[G]; retire gll(c) only
    asm volatile("s_waitcnt vmcnt(%0)" :: "n"(G + S) : "memory");
    __builtin_amdgcn_s_barrier();
    compute(b + c * 256, c & 1);
    __builtin_amdgcn_s_barrier();
  }
  {  // final chunk: retire gll(last), leave stores(prev) in flight
    asm volatile("s_waitcnt vmcnt(%0)" :: "n"(S) : "memory");
    __builtin_amdgcn_s_barrier();
    compute(b + c * 256, c & 1);
  }
#undef LDAF
}

__global__ __launch_bounds__(512, 1) void irrep_linear_k(
    const float* __restrict__ x, const v8h* __restrict__ frag, float* __restrict__ out,
    int n_tiles) {
  __shared__ __align__(16) unsigned char sm[2 * 61440];
  const int t = threadIdx.x;
  const int b = blockIdx.x;
  const int nc = (n_tiles - b + 255) >> 8;    // chunks for this block (24 or 25)
  const int w = t >> 6;
  if (w < 2)      wave_main<0, 8>(x, frag, out, sm, t, b, nc);
  else if (w < 4) wave_main<1, 8>(x, frag, out, sm, t, b, nc);
  else if (w < 6) wave_main<1, 7>(x, frag, out, sm, t, b, nc);
  else            wave_main<2, 7>(x, frag, out, sm, t, b, nc);
}

extern "C" void kernel_launch(void* const* d_in, const int* in_sizes, int n_in,
                              void* d_out, int out_size, void* d_ws, size_t ws_size,
                              hipStream_t stream) {
  const float* x  = (const float*)d_in[0];
  const float* W0 = (const float*)d_in[1];
  const float* W1 = (const float*)d_in[2];
  const float* W2 = (const float*)d_in[3];
  float* out = (float*)d_out;
  v8h* frag = (v8h*)d_ws;   // 154 * 64 * 16 B = 157,696 B

  build_frags_k<<<154, 64, 0, stream>>>(W0, W1, W2, frag);

  const int N = in_sizes[0] / 480;        // 200000
  const int n_tiles = N / 32;             // 6250 tiles of 32 rows
  irrep_linear_k<<<256, 512, 0, stream>>>(x, frag, out, n_tiles);
}

// Round 15
// 150.214 us; speedup vs baseline: 2.0314x; 1.0368x over previous
//
#include <hip/hip_runtime.h>

typedef _Float16 v8h __attribute__((ext_vector_type(8)));
typedef float    v4f __attribute__((ext_vector_type(4)));

#define MFMA16(a, b, c) __builtin_amdgcn_mfma_f32_16x16x32_f16((a), (b), (c), 0, 0, 0)

#define GLL16(gptr, lptr)                                                        \
  __builtin_amdgcn_global_load_lds((const __attribute__((address_space(1))) void*)(gptr), \
                                   (__attribute__((address_space(3))) void*)(lptr), 16, 0, 0)

// Weight-fragment table in d_ws: 154 fragments, layout [frag][lane] of 8 x f16 (16B).
// Non-zero 32(k) x 16(n) tiles of the 480x480 block-diagonal Wbig:
//   ot 0..7   (cols   0..127): kt 0..3   fbase = ot*4
//   ot 8..19  (cols 128..319): kt 4..9   fbase = 32 + (ot-8)*6
//   ot 20..29 (cols 320..479): kt 10..14 fbase = 104 + (ot-20)*5
// Fragment convention (A and B slots identical): lane l, elem e holds
// k = kt*32 + (l>>4)*8 + e; other dim = l&15.
// SWAPPED use: W-frag in A slot, x-frag in B slot -> lane l, reg j =
// out[row l&15][col ot*16 + (l>>4)*4 + j] -> one float4 store per ot.

__global__ void build_frags_k(const float* __restrict__ W0, const float* __restrict__ W1,
                              const float* __restrict__ W2, v8h* __restrict__ frag) {
  const int f = blockIdx.x;
  const int lane = threadIdx.x;
  int ot, kt;
  if (f < 32)       { ot = f >> 2;           kt = f & 3; }
  else if (f < 104) { int q = f - 32;  ot = 8 + q / 6;  kt = 4 + q % 6; }
  else              { int q = f - 104; ot = 20 + q / 5; kt = 10 + q % 5; }
  const int n  = ot * 16 + (lane & 15);
  const int kb = kt * 32 + (lane >> 4) * 8;
  v8h v;
#pragma unroll
  for (int e = 0; e < 8; ++e) {
    const int k = kb + e;
    float wv = 0.0f;
    if (k < 128) {
      if (n < 128) wv = W0[k * 128 + n] * 0.08838834764831845f;           // 1/sqrt(128)
    } else if (k < 320) {
      if (n >= 128 && n < 320) {
        const int i = k - 128, o = n - 128;
        if (i % 3 == o % 3) wv = W1[(i / 3) * 64 + (o / 3)] * 0.125f;     // 1/sqrt(64)
      }
    } else {
      if (n >= 320) {
        const int i = k - 320, o = n - 320;
        if (i % 5 == o % 5) wv = W2[(i / 5) * 32 + (o / 5)] * 0.17677669529663687f; // 1/sqrt(32)
      }
    }
    v[e] = (_Float16)wv;
  }
  frag[f * 64 + lane] = v;
}

// Persistent 512-thread blocks, 1/CU. 16-row tiles (30720B) in a 4-slot LDS
// ring, staged 2 ahead via global_load_lds (source-side bank swizzle),
// GRID-STRIDE tile assignment (round-14 win), col-block wave partition
// (round-13 win), and ONE barrier per tile:
//   iter c: stage(c+2) -> vmcnt(2G+2S) -> s_barrier -> compute(c)
// Ring safety: between consecutive barriers the concurrent LDS ops are
// compute(c) [slot c&3] and stage(c+3) [slot (c+3)&3] — distance 3 mod 4.
// vmcnt: issue order ...gll(c),S(c-2),gll(c+1),S(c-1),gll(c+2) -> 2G+2S
// retires exactly gll(c); peeled iters 2G / 2G+S / G+2S / 2S.
// Partition: V=0 (w0,1) cb0 kts0-3 ots{w+2i}; V=1 (w2..5) cb1 kts4-9
// ots{6+w+4i}; V=2 (w6,7) cb2 kts10-14 ots{14+w+2i}.
// Staging: 30 x 1024B wave-instructions: waves 0-5 G=4, waves 6-7 G=3.
template <int V, int G>
__device__ __forceinline__ void wave_main(const float* __restrict__ x,
                                          const v8h* __restrict__ frag,
                                          float* __restrict__ out,
                                          unsigned char* sm, int t, int b, int nc) {
  const int lane = t & 63;
  const int w    = t >> 6;
  const int r16  = lane & 15;
  const int g    = lane >> 4;

  constexpr int S  = (V == 0) ? 4 : (V == 1) ? 3 : 5;    // stores per tile
  constexpr int NF = (V == 0) ? 16 : (V == 1) ? 18 : 25; // resident frags

  // ---- persistent B-fragments (compile-time indices) ----
  v8h f[NF];
  if constexpr (V == 0) {
#pragma unroll
    for (int i = 0; i < 4; ++i)
#pragma unroll
      for (int k = 0; k < 4; ++k)
        f[i * 4 + k] = frag[((w + 2 * i) * 4 + k) * 64 + lane];
  } else if constexpr (V == 1) {
#pragma unroll
    for (int i = 0; i < 3; ++i)
#pragma unroll
      for (int k = 0; k < 6; ++k)
        f[i * 6 + k] = frag[(32 + (w - 2 + 4 * i) * 6 + k) * 64 + lane];
  } else {
#pragma unroll
    for (int i = 0; i < 5; ++i)
#pragma unroll
      for (int k = 0; k < 5; ++k)
        f[i * 5 + k] = frag[(104 + (w - 6 + 2 * i) * 5 + k) * 64 + lane];
  }

  // ---- staging: 16 rows x 1920B = 1920 granules; G gll per wave ----
  auto stage = [&](int tt, int slot) {
    const unsigned char* xt = (const unsigned char*)x + (size_t)tt * 30720u;
    unsigned char* buf = sm + (size_t)slot * 30720u;
#pragma unroll
    for (int i = 0; i < 4; ++i) {
      if (i < 3 || w < 6) {                    // wave-uniform; waves 0..5 do i=3
        const unsigned gl = (unsigned)(i * 512 + t);
        const unsigned r  = gl / 120u;
        const unsigned j  = gl - r * 120u;
        GLL16(xt + r * 1920u + ((j ^ (r & 7u)) << 4), buf + i * 8192 + w * 1024);
      }
    }
  };

#define LDAF(kt, dst)                                                                       \
  {                                                                                         \
    const unsigned j0 = (unsigned)((kt) * 8 + g * 2);                                       \
    const float4 lo = *reinterpret_cast<const float4*>(smc + rb + (((j0) ^ q) << 4));       \
    const float4 hi = *reinterpret_cast<const float4*>(smc + rb + ((((j0) + 1) ^ q) << 4)); \
    v8h v_;                                                                                 \
    v_[0] = (_Float16)lo.x; v_[1] = (_Float16)lo.y;                                         \
    v_[2] = (_Float16)lo.z; v_[3] = (_Float16)lo.w;                                         \
    v_[4] = (_Float16)hi.x; v_[5] = (_Float16)hi.y;                                         \
    v_[6] = (_Float16)hi.z; v_[7] = (_Float16)hi.w;                                         \
    dst = v_;                                                                               \
  }

  auto compute = [&](int tt, int slot) {
    const unsigned char* smc = sm + (size_t)slot * 30720u;
    const unsigned rb = (unsigned)r16 * 1920u;
    const unsigned q  = (unsigned)(r16 & 7u);
    float* const ob = out + ((size_t)tt * 16 + r16) * 480 + g * 4;
    if constexpr (V == 0) {
      v8h xr[4];
#pragma unroll
      for (int k = 0; k < 4; ++k) LDAF(k, xr[k]);
#pragma unroll
      for (int i = 0; i < 4; ++i) {
        v4f a = {0.f, 0.f, 0.f, 0.f};
#pragma unroll
        for (int k = 0; k < 4; ++k) a = MFMA16(f[i * 4 + k], xr[k], a);
        *reinterpret_cast<v4f*>(ob + (w + 2 * i) * 16) = a;
      }
    } else if constexpr (V == 1) {
      v8h xr[6];
#pragma unroll
      for (int k = 0; k < 6; ++k) LDAF(4 + k, xr[k]);
#pragma unroll
      for (int i = 0; i < 3; ++i) {
        v4f a = {0.f, 0.f, 0.f, 0.f};
#pragma unroll
        for (int k = 0; k < 6; ++k) a = MFMA16(f[i * 6 + k], xr[k], a);
        *reinterpret_cast<v4f*>(ob + (6 + w + 4 * i) * 16) = a;
      }
    } else {
      v8h xr[5];
#pragma unroll
      for (int k = 0; k < 5; ++k) LDAF(10 + k, xr[k]);
#pragma unroll
      for (int i = 0; i < 5; ++i) {
        v4f a = {0.f, 0.f, 0.f, 0.f};
#pragma unroll
        for (int k = 0; k < 5; ++k) a = MFMA16(f[i * 5 + k], xr[k], a);
        *reinterpret_cast<v4f*>(ob + (14 + w + 2 * i) * 16) = a;
      }
    }
  };

#define PIPE(C, N)                                              \
  {                                                             \
    asm volatile("s_waitcnt vmcnt(%0)" :: "n"(N) : "memory");   \
    __builtin_amdgcn_s_barrier();                               \
    compute(b + (C) * 256, (C) & 3);                            \
  }

  // ---- single-barrier ring-4 loop over grid-stride chunks (nc >= 4) ----
  stage(b, 0);
  stage(b + 256, 1);
  stage(b + 2 * 256, 2); PIPE(0, 2 * G)
  stage(b + 3 * 256, 3); PIPE(1, 2 * G + S)
  for (int c = 2; c <= nc - 3; ++c) {
    stage(b + (c + 2) * 256, (c + 2) & 3);
    PIPE(c, 2 * G + 2 * S)
  }
  PIPE(nc - 2, G + 2 * S)
  PIPE(nc - 1, 2 * S)
#undef PIPE
#undef LDAF
}

__global__ __launch_bounds__(512, 1) void irrep_linear_k(
    const float* __restrict__ x, const v8h* __restrict__ frag, float* __restrict__ out,
    int n_tiles) {
  __shared__ __align__(16) unsigned char sm[4 * 30720];
  const int t = threadIdx.x;
  const int b = blockIdx.x;
  const int nc = (n_tiles - b + 255) >> 8;    // 48 or 49 grid-stride chunks
  const int w = t >> 6;
  if (w < 2)      wave_main<0, 4>(x, frag, out, sm, t, b, nc);
  else if (w < 6) wave_main<1, 4>(x, frag, out, sm, t, b, nc);
  else            wave_main<2, 3>(x, frag, out, sm, t, b, nc);
}

extern "C" void kernel_launch(void* const* d_in, const int* in_sizes, int n_in,
                              void* d_out, int out_size, void* d_ws, size_t ws_size,
                              hipStream_t stream) {
  const float* x  = (const float*)d_in[0];
  const float* W0 = (const float*)d_in[1];
  const float* W1 = (const float*)d_in[2];
  const float* W2 = (const float*)d_in[3];
  float* out = (float*)d_out;
  v8h* frag = (v8h*)d_ws;   // 154 * 64 * 16 B = 157,696 B

  build_frags_k<<<154, 64, 0, stream>>>(W0, W1, W2, frag);

  const int N = in_sizes[0] / 480;        // 200000
  const int n_tiles = N / 16;             // 12500 tiles of 16 rows
  irrep_linear_k<<<256, 512, 0, stream>>>(x, frag, out, n_tiles);
}